// Round 7
// baseline (161.570 us; speedup 1.0000x reference)
//
#include <hip/hip_runtime.h>
#include <hip/hip_fp16.h>

#define N_NODES 131072
#define N_EDGES 4194304
#define NUM_GRAPHS 128

#define NB 512        // buckets
#define NPB 256       // nodes per bucket (N_NODES / NB)
#define BSHIFT 8      // dst>>8 = bucket, dst&255 = local node
#define BCAP 10240    // slots per bucket (mean 8192, sd ~90 -> +22 sigma)
#define GSPAN 8       // max graphs tracked in LDS per bucket (fallback: global)

// ---------------- init per-bucket cursors -------------------------------------
__global__ __launch_bounds__(512) void k_init(int* __restrict__ bcursor) {
  bcursor[threadIdx.x] = threadIdx.x * BCAP;
}

// ------- bin edges by dst bucket; batch-reserved contiguous runs ---------------
__global__ __launch_bounds__(1024) void k_binfill(const int* __restrict__ src,
                                                  const int* __restrict__ dst,
                                                  int* __restrict__ bcursor,
                                                  unsigned* __restrict__ binned) {
  __shared__ int hist[NB], base_[NB], rank_[NB];
  for (int k = threadIdx.x; k < NB; k += 1024) { hist[k] = 0; rank_[k] = 0; }
  __syncthreads();
  unsigned pk[16];
  int bk[16];
  int eb = blockIdx.x * 16384 + threadIdx.x;
  #pragma unroll
  for (int i = 0; i < 16; ++i) {
    int e = eb + i * 1024;
    int s = __builtin_nontemporal_load(&src[e]);
    int d = __builtin_nontemporal_load(&dst[e]);
    bk[i] = d >> BSHIFT;
    pk[i] = ((unsigned)s << BSHIFT) | (unsigned)(d & (NPB - 1));
    atomicAdd(&hist[bk[i]], 1);
  }
  __syncthreads();
  for (int k = threadIdx.x; k < NB; k += 1024)
    base_[k] = atomicAdd(&bcursor[k], hist[k]);
  __syncthreads();
  #pragma unroll
  for (int i = 0; i < 16; ++i) {
    int r = atomicAdd(&rank_[bk[i]], 1);
    binned[base_[bk[i]] + r] = pk[i];
  }
}

// ------- per-bucket counting sort (LDS scatter) -> coalesced CSR ---------------
// also: dinv, xs = dinv*x (padded float4), node_off, cnt
__global__ __launch_bounds__(1024) void k_sortB(const unsigned* __restrict__ binned,
                                                const int* __restrict__ bcursor,
                                                const float* __restrict__ x,
                                                float* __restrict__ dinv,
                                                float4* __restrict__ xs4,
                                                int* __restrict__ node_off,
                                                int* __restrict__ cnt,
                                                int* __restrict__ csrg) {
  __shared__ int dcount[NPB];
  __shared__ int cursor[NPB];
  __shared__ int wsum[4];
  __shared__ int csrL[BCAP];  // 40 KB
  int tid = threadIdx.x;
  if (tid < NPB) dcount[tid] = 0;
  __syncthreads();
  int b = blockIdx.x;
  int s0 = b * BCAP;
  int n = bcursor[b] - s0;

  unsigned ent_r[10];
  #pragma unroll
  for (int j = 0; j < 10; ++j) {
    int e = tid + j * 1024;
    if (e < n) {
      unsigned ent = __builtin_nontemporal_load(&binned[s0 + e]);
      ent_r[j] = ent;
      atomicAdd(&dcount[ent & (NPB - 1)], 1);
    }
  }
  __syncthreads();

  int v = 0, incl = 0;
  if (tid < NPB) {
    v = dcount[tid];
    incl = v;
    #pragma unroll
    for (int d = 1; d < 64; d <<= 1) {
      int t = __shfl_up(incl, d);
      if ((tid & 63) >= d) incl += t;
    }
    if ((tid & 63) == 63) wsum[tid >> 6] = incl;
  }
  __syncthreads();
  if (tid < NPB) {
    int base = 0;
    int wv = tid >> 6;
    for (int w2 = 0; w2 < wv; ++w2) base += wsum[w2];
    int pref = base + incl - v;  // exclusive prefix within bucket
    cursor[tid] = pref;
    int node = b * NPB + tid;
    node_off[node] = pref;
    cnt[node] = v;
    float di = rsqrtf((float)(v + 1));  // +1: self-loop
    dinv[node] = di;
    xs4[node] = make_float4(di * x[node * 3 + 0], di * x[node * 3 + 1],
                            di * x[node * 3 + 2], 0.f);
  }
  __syncthreads();

  #pragma unroll
  for (int j = 0; j < 10; ++j) {
    int e = tid + j * 1024;
    if (e < n) {
      unsigned ent = ent_r[j];
      int pos = atomicAdd(&cursor[ent & (NPB - 1)], 1);
      csrL[pos] = (int)(ent >> BSHIFT);  // random LDS write, bank-spread
    }
  }
  __syncthreads();

  #pragma unroll
  for (int j = 0; j < 10; ++j) {
    int e = tid + j * 1024;
    if (e < n) csrg[s0 + e] = csrL[e];   // coalesced global write
  }
}

// ------- fused: CSR gather-agg of xs (3 feats) + W1 proj + relu -> fp16 --------
__global__ __launch_bounds__(1024) void k_agg3h1(const int* __restrict__ csrg,
                                                 const int* __restrict__ node_off,
                                                 const int* __restrict__ cnt,
                                                 const float* __restrict__ xs,
                                                 const float4* __restrict__ xs4,
                                                 const float* __restrict__ dinv,
                                                 const float* __restrict__ W1,
                                                 const float* __restrict__ b1,
                                                 unsigned* __restrict__ h1h) {
  __shared__ float w[48];
  __shared__ float bb[16];
  __shared__ float accS[NPB * 4];
  if (threadIdx.x < 48) w[threadIdx.x] = W1[threadIdx.x];
  if (threadIdx.x >= 64 && threadIdx.x < 80) bb[threadIdx.x - 64] = b1[threadIdx.x - 64];

  int b = blockIdx.x;
  int dl = threadIdx.x >> 2;
  int q = threadIdx.x & 3;
  int node = b * NPB + dl;
  int s0 = b * BCAP + node_off[node];
  int len = cnt[node];
  float acc = 0.f;
  #pragma unroll 4
  for (int k = 0; k < len; ++k) {
    int srcn = __builtin_nontemporal_load(&csrg[s0 + k]);  // broadcast, stream
    acc += xs[srcn * 4 + q];          // lanes 0..3 read 16B contiguous
  }
  accS[threadIdx.x] = acc;
  __syncthreads();

  float di = dinv[node];
  float4 xself = xs4[node];
  float a0 = di * (accS[dl * 4 + 0] + xself.x);
  float a1 = di * (accS[dl * 4 + 1] + xself.y);
  float a2 = di * (accS[dl * 4 + 2] + xself.z);
  float o[4];
  #pragma unroll
  for (int j = 0; j < 4; ++j) {
    int cc = q * 4 + j;
    float vv = a0 * w[cc] + a1 * w[16 + cc] + a2 * w[32 + cc] + bb[cc];
    o[j] = di * fmaxf(vv, 0.f);
  }
  __half2 p0 = __floats2half2_rn(o[0], o[1]);
  __half2 p1 = __floats2half2_rn(o[2], o[3]);
  uint2 st;
  st.x = *reinterpret_cast<unsigned*>(&p0);
  st.y = *reinterpret_cast<unsigned*>(&p1);
  *(uint2*)(h1h + (size_t)node * 8 + q * 2) = st;
}

// ------- CSR gather-agg of h1 + fused h2 = relu(agg@W2+b2) + per-graph pool ----
__global__ __launch_bounds__(1024) void k_agg16pool(const int* __restrict__ csrg,
                                                    const int* __restrict__ node_off,
                                                    const int* __restrict__ cnt,
                                                    const unsigned* __restrict__ h1h,
                                                    const float* __restrict__ dinv,
                                                    const int* __restrict__ batch,
                                                    const float* __restrict__ W2,
                                                    const float* __restrict__ b2,
                                                    float* __restrict__ gsum) {
  __shared__ float aggS[NPB * 16];   // 16 KB: agg row per node
  __shared__ float w2s[1024];        // 4 KB
  __shared__ float b2s[64];
  __shared__ float gacc[GSPAN * 64]; // 2 KB per-graph partial sums
  w2s[threadIdx.x] = W2[threadIdx.x];
  if (threadIdx.x < 64) b2s[threadIdx.x] = b2[threadIdx.x];
  if (threadIdx.x < GSPAN * 64) gacc[threadIdx.x] = 0.f;

  int b = blockIdx.x;
  // ---- phase A: per-node aggregation into LDS (4 lanes/node, reg accumulate) --
  int dl = threadIdx.x >> 2;
  int q = threadIdx.x & 3;
  int node = b * NPB + dl;
  int s0 = b * BCAP + node_off[node];
  int len = cnt[node];
  float o0 = 0.f, o1 = 0.f, o2 = 0.f, o3 = 0.f;
  #pragma unroll 4
  for (int k = 0; k < len; ++k) {
    int srcn = __builtin_nontemporal_load(&csrg[s0 + k]);       // stream
    uint2 hv = *(const uint2*)(h1h + (size_t)srcn * 8 + q * 2); // 4 lanes = 32B row
    __half2 p0 = *reinterpret_cast<const __half2*>(&hv.x);
    __half2 p1 = *reinterpret_cast<const __half2*>(&hv.y);
    o0 += __low2float(p0); o1 += __high2float(p0);
    o2 += __low2float(p1); o3 += __high2float(p1);
  }
  float di = dinv[node];
  uint2 sv = *(const uint2*)(h1h + (size_t)node * 8 + q * 2);
  __half2 s0h = *reinterpret_cast<const __half2*>(&sv.x);
  __half2 s1h = *reinterpret_cast<const __half2*>(&sv.y);
  aggS[dl * 16 + 4 * q + 0] = di * (o0 + __low2float(s0h));
  aggS[dl * 16 + 4 * q + 1] = di * (o1 + __high2float(s0h));
  aggS[dl * 16 + 4 * q + 2] = di * (o2 + __low2float(s1h));
  aggS[dl * 16 + 4 * q + 3] = di * (o3 + __high2float(s1h));
  __syncthreads();

  // ---- phase B: h2 = relu(agg@W2+b2), pool by graph (wave-uniform node) -------
  int c = threadIdx.x & 63;
  int slot = threadIdx.x >> 6;  // 16 waves, one node per wave per iter
  int g0 = batch[b * NPB];      // first graph in bucket (non-decreasing)
  float racc = 0.f;
  int curli = -1;
  for (int nloc = slot; nloc < NPB; nloc += 16) {
    int nd = b * NPB + nloc;
    int li = batch[nd] - g0;    // wave-uniform
    if (li != curli) {
      if (curli >= 0) {
        if (curli < GSPAN) atomicAdd(&gacc[curli * 64 + c], racc);
        else atomicAdd(&gsum[(size_t)(g0 + curli) * 64 + c], racc);
      }
      curli = li;
      racc = 0.f;
    }
    float v = b2s[c];
    const float* ar = &aggS[nloc * 16];
    #pragma unroll
    for (int k = 0; k < 16; ++k) v += ar[k] * w2s[k * 64 + c];  // broadcast reads
    racc += fmaxf(v, 0.f);
  }
  if (curli >= 0) {
    if (curli < GSPAN) atomicAdd(&gacc[curli * 64 + c], racc);
    else atomicAdd(&gsum[(size_t)(g0 + curli) * 64 + c], racc);
  }
  __syncthreads();

  // ---- flush LDS partials to global -------------------------------------------
  int span = batch[b * NPB + NPB - 1] - g0 + 1;
  if (span > GSPAN) span = GSPAN;
  for (int li = threadIdx.x >> 6; li < span; li += 16) {
    float v = gacc[li * 64 + c];
    atomicAdd(&gsum[(size_t)(g0 + li) * 64 + c], v);
  }
}

// ---- final: per-graph mean + FC MLP (64->32->2) --------------------------------
__global__ __launch_bounds__(64) void k_fc(const float* __restrict__ gsum,
                                           const int* __restrict__ batch,
                                           const float* __restrict__ fcw1,
                                           const float* __restrict__ fcb1,
                                           const float* __restrict__ fcw2,
                                           const float* __restrict__ fcb2,
                                           float* __restrict__ out) {
  int g = blockIdx.x;
  int lo = 0, hi = N_NODES;
  while (lo < hi) { int m = (lo + hi) >> 1; if (batch[m] < g) lo = m + 1; else hi = m; }
  int start = lo;
  lo = start; hi = N_NODES;
  while (lo < hi) { int m = (lo + hi) >> 1; if (batch[m] < g + 1) lo = m + 1; else hi = m; }
  float inv = 1.0f / fmaxf((float)(lo - start), 1.0f);

  __shared__ float gmean[64];
  gmean[threadIdx.x] = gsum[(size_t)g * 64 + threadIdx.x] * inv;
  __syncthreads();

  __shared__ float hid[32];
  if (threadIdx.x < 32) {
    float a = fcb1[threadIdx.x];
    #pragma unroll
    for (int k = 0; k < 64; ++k) a += gmean[k] * fcw1[k * 32 + threadIdx.x];
    hid[threadIdx.x] = a;
  }
  __syncthreads();

  if (threadIdx.x < 2) {
    float a = fcb2[threadIdx.x];
    #pragma unroll
    for (int k = 0; k < 32; ++k) a += hid[k] * fcw2[k * 2 + threadIdx.x];
    out[g * 2 + threadIdx.x] = a;
  }
}

extern "C" void kernel_launch(void* const* d_in, const int* in_sizes, int n_in,
                              void* d_out, int out_size, void* d_ws, size_t ws_size,
                              hipStream_t stream) {
  const float* x    = (const float*)d_in[0];
  const int*   ei   = (const int*)d_in[1];
  const int*   batch= (const int*)d_in[2];
  const float* W1   = (const float*)d_in[3];
  const float* b1   = (const float*)d_in[4];
  const float* W2   = (const float*)d_in[5];
  const float* b2   = (const float*)d_in[6];
  const float* fcw1 = (const float*)d_in[7];
  const float* fcb1 = (const float*)d_in[8];
  const float* fcw2 = (const float*)d_in[9];
  const float* fcb2 = (const float*)d_in[10];
  float* out = (float*)d_out;

  char* w = (char*)d_ws;
  size_t off = 0;
  auto alloc = [&](size_t bytes) {
    void* p = w + off;
    off += (bytes + 255) & ~(size_t)255;
    return p;
  };
  int*      bcursor  = (int*)     alloc((size_t)NB * 4);
  unsigned* binned   = (unsigned*)alloc((size_t)NB * BCAP * 4);  // 21 MB
  int*      csrg     = (int*)     alloc((size_t)NB * BCAP * 4);  // 21 MB
  float*    dinv     = (float*)   alloc((size_t)N_NODES * 4);
  float4*   xs4      = (float4*)  alloc((size_t)N_NODES * 16);   // 2 MB
  int*      node_off = (int*)     alloc((size_t)N_NODES * 4);
  int*      cnt      = (int*)     alloc((size_t)N_NODES * 4);
  unsigned* h1h      = (unsigned*)alloc((size_t)N_NODES * 32);   // 4 MB fp16
  float*    gsum     = (float*)   alloc((size_t)NUM_GRAPHS * 64 * 4);

  const int* srcp = ei;
  const int* dstp = ei + N_EDGES;

  hipMemsetAsync(gsum, 0, (size_t)NUM_GRAPHS * 64 * 4, stream);
  k_init<<<1, 512, 0, stream>>>(bcursor);
  k_binfill<<<N_EDGES / 16384, 1024, 0, stream>>>(srcp, dstp, bcursor, binned);
  k_sortB<<<NB, 1024, 0, stream>>>(binned, bcursor, x, dinv, xs4, node_off, cnt, csrg);
  k_agg3h1<<<NB, 1024, 0, stream>>>(csrg, node_off, cnt, (const float*)xs4, xs4, dinv, W1, b1, h1h);
  k_agg16pool<<<NB, 1024, 0, stream>>>(csrg, node_off, cnt, h1h, dinv, batch, W2, b2, gsum);
  k_fc<<<NUM_GRAPHS, 64, 0, stream>>>(gsum, batch, fcw1, fcb1, fcw2, fcb2, out);
}

// Round 8
// 126.782 us; speedup vs baseline: 1.2744x; 1.2744x over previous
//
#include <hip/hip_runtime.h>
#include <hip/hip_fp16.h>

#define N_NODES 131072
#define N_EDGES 4194304
#define NUM_GRAPHS 128

#define NB 512        // buckets
#define NPB 256       // nodes per bucket (N_NODES / NB)
#define BSHIFT 8      // dst>>8 = bucket, dst&255 = local node
#define BCAP 10240    // slots per bucket (mean 8192, sd ~90 -> +22 sigma)
#define GSPAN 8       // max graphs tracked in LDS per bucket (fallback: global)

// ---------------- init per-bucket cursors -------------------------------------
__global__ __launch_bounds__(512) void k_init(int* __restrict__ bcursor) {
  bcursor[threadIdx.x] = threadIdx.x * BCAP;
}

// ------- bin edges by dst bucket; batch-reserved contiguous runs ---------------
__global__ __launch_bounds__(1024) void k_binfill(const int* __restrict__ src,
                                                  const int* __restrict__ dst,
                                                  int* __restrict__ bcursor,
                                                  unsigned* __restrict__ binned) {
  __shared__ int hist[NB], base_[NB], rank_[NB];
  for (int k = threadIdx.x; k < NB; k += 1024) { hist[k] = 0; rank_[k] = 0; }
  __syncthreads();
  unsigned pk[16];
  int bk[16];
  int eb = blockIdx.x * 16384 + threadIdx.x;
  #pragma unroll
  for (int i = 0; i < 16; ++i) {
    int e = eb + i * 1024;
    int s = __builtin_nontemporal_load(&src[e]);
    int d = __builtin_nontemporal_load(&dst[e]);
    bk[i] = d >> BSHIFT;
    pk[i] = ((unsigned)s << BSHIFT) | (unsigned)(d & (NPB - 1));
    atomicAdd(&hist[bk[i]], 1);
  }
  __syncthreads();
  for (int k = threadIdx.x; k < NB; k += 1024)
    base_[k] = atomicAdd(&bcursor[k], hist[k]);
  __syncthreads();
  #pragma unroll
  for (int i = 0; i < 16; ++i) {
    int r = atomicAdd(&rank_[bk[i]], 1);
    binned[base_[bk[i]] + r] = pk[i];
  }
}

// ------- per-bucket counting sort (LDS scatter) -> coalesced CSR ---------------
// also: dinv, xs = dinv*x (padded float4), node_off, cnt
__global__ __launch_bounds__(1024) void k_sortB(const unsigned* __restrict__ binned,
                                                const int* __restrict__ bcursor,
                                                const float* __restrict__ x,
                                                float* __restrict__ dinv,
                                                float4* __restrict__ xs4,
                                                int* __restrict__ node_off,
                                                int* __restrict__ cnt,
                                                int* __restrict__ csrg) {
  __shared__ int dcount[NPB];
  __shared__ int cursor[NPB];
  __shared__ int wsum[4];
  __shared__ int csrL[BCAP];  // 40 KB
  int tid = threadIdx.x;
  if (tid < NPB) dcount[tid] = 0;
  __syncthreads();
  int b = blockIdx.x;
  int s0 = b * BCAP;
  int n = bcursor[b] - s0;

  unsigned ent_r[10];
  #pragma unroll
  for (int j = 0; j < 10; ++j) {
    int e = tid + j * 1024;
    if (e < n) {
      unsigned ent = __builtin_nontemporal_load(&binned[s0 + e]);
      ent_r[j] = ent;
      atomicAdd(&dcount[ent & (NPB - 1)], 1);
    }
  }
  __syncthreads();

  int v = 0, incl = 0;
  if (tid < NPB) {
    v = dcount[tid];
    incl = v;
    #pragma unroll
    for (int d = 1; d < 64; d <<= 1) {
      int t = __shfl_up(incl, d);
      if ((tid & 63) >= d) incl += t;
    }
    if ((tid & 63) == 63) wsum[tid >> 6] = incl;
  }
  __syncthreads();
  if (tid < NPB) {
    int base = 0;
    int wv = tid >> 6;
    for (int w2 = 0; w2 < wv; ++w2) base += wsum[w2];
    int pref = base + incl - v;  // exclusive prefix within bucket
    cursor[tid] = pref;
    int node = b * NPB + tid;
    node_off[node] = pref;
    cnt[node] = v;
    float di = rsqrtf((float)(v + 1));  // +1: self-loop
    dinv[node] = di;
    xs4[node] = make_float4(di * x[node * 3 + 0], di * x[node * 3 + 1],
                            di * x[node * 3 + 2], 0.f);
  }
  __syncthreads();

  #pragma unroll
  for (int j = 0; j < 10; ++j) {
    int e = tid + j * 1024;
    if (e < n) {
      unsigned ent = ent_r[j];
      int pos = atomicAdd(&cursor[ent & (NPB - 1)], 1);
      csrL[pos] = (int)(ent >> BSHIFT);  // random LDS write, bank-spread
    }
  }
  __syncthreads();

  #pragma unroll
  for (int j = 0; j < 10; ++j) {
    int e = tid + j * 1024;
    if (e < n) csrg[s0 + e] = csrL[e];   // coalesced global write
  }
}

// ------- fused: CSR gather-agg of xs (3 feats) + W1 proj + relu -> fp16 --------
__global__ __launch_bounds__(1024) void k_agg3h1(const int* __restrict__ csrg,
                                                 const int* __restrict__ bcursor,
                                                 const int* __restrict__ node_off,
                                                 const int* __restrict__ cnt,
                                                 const float* __restrict__ xs,
                                                 const float4* __restrict__ xs4,
                                                 const float* __restrict__ dinv,
                                                 const float* __restrict__ W1,
                                                 const float* __restrict__ b1,
                                                 unsigned* __restrict__ h1h) {
  __shared__ int csrL[BCAP];  // 40 KB
  __shared__ float w[48];
  __shared__ float bb[16];
  __shared__ float accS[NPB * 4];
  if (threadIdx.x < 48) w[threadIdx.x] = W1[threadIdx.x];
  if (threadIdx.x >= 64 && threadIdx.x < 80) bb[threadIdx.x - 64] = b1[threadIdx.x - 64];

  int b = blockIdx.x;
  int s0 = b * BCAP;
  int n = bcursor[b] - s0;
  for (int e = threadIdx.x; e < n; e += 1024)
    csrL[e] = __builtin_nontemporal_load(&csrg[s0 + e]);
  __syncthreads();

  int dl = threadIdx.x >> 2;
  int q = threadIdx.x & 3;
  int node = b * NPB + dl;
  int off = node_off[node];
  int len = cnt[node];
  float acc = 0.f;
  #pragma unroll 8
  for (int k = 0; k < len; ++k) {
    int srcn = csrL[off + k];         // LDS broadcast to 4 lanes
    acc += xs[srcn * 4 + q];          // lanes 0..3 read 16B contiguous
  }
  accS[threadIdx.x] = acc;
  __syncthreads();

  float di = dinv[node];
  float4 xself = xs4[node];
  float a0 = di * (accS[dl * 4 + 0] + xself.x);
  float a1 = di * (accS[dl * 4 + 1] + xself.y);
  float a2 = di * (accS[dl * 4 + 2] + xself.z);
  float o[4];
  #pragma unroll
  for (int j = 0; j < 4; ++j) {
    int cc = q * 4 + j;
    float vv = a0 * w[cc] + a1 * w[16 + cc] + a2 * w[32 + cc] + bb[cc];
    o[j] = di * fmaxf(vv, 0.f);
  }
  __half2 p0 = __floats2half2_rn(o[0], o[1]);
  __half2 p1 = __floats2half2_rn(o[2], o[3]);
  uint2 st;
  st.x = *reinterpret_cast<unsigned*>(&p0);
  st.y = *reinterpret_cast<unsigned*>(&p1);
  *(uint2*)(h1h + (size_t)node * 8 + q * 2) = st;
}

// ------- CSR gather-agg of h1 + fused h2 = relu(agg@W2+b2) + per-graph pool ----
__global__ __launch_bounds__(1024) void k_agg16pool(const int* __restrict__ csrg,
                                                    const int* __restrict__ bcursor,
                                                    const int* __restrict__ node_off,
                                                    const int* __restrict__ cnt,
                                                    const unsigned* __restrict__ h1h,
                                                    const float* __restrict__ dinv,
                                                    const int* __restrict__ batch,
                                                    const float* __restrict__ W2,
                                                    const float* __restrict__ b2,
                                                    float* __restrict__ gsum) {
  __shared__ int csrL[BCAP];         // 40 KB
  __shared__ float aggS[NPB * 16];   // 16 KB
  __shared__ float w2s[1024];        // 4 KB
  __shared__ float b2s[64];
  __shared__ float gacc[GSPAN * 64]; // 2 KB
  w2s[threadIdx.x] = W2[threadIdx.x];
  if (threadIdx.x < 64) b2s[threadIdx.x] = b2[threadIdx.x];
  if (threadIdx.x < GSPAN * 64) gacc[threadIdx.x] = 0.f;

  int b = blockIdx.x;
  int s0 = b * BCAP;
  int n = bcursor[b] - s0;
  for (int e = threadIdx.x; e < n; e += 1024)
    csrL[e] = __builtin_nontemporal_load(&csrg[s0 + e]);
  __syncthreads();

  // ---- phase A: per-node aggregation into LDS (8 lanes/node, 2 halves) --------
  int q = threadIdx.x & 7;       // 4B = 2 fp16 feats per lane
  int nl0 = threadIdx.x >> 3;    // 0..127
  #pragma unroll
  for (int half = 0; half < 2; ++half) {
    int dl = nl0 + half * 128;
    int node = b * NPB + dl;
    int off = node_off[node];
    int len = cnt[node];
    float o0 = 0.f, o1 = 0.f;
    #pragma unroll 8
    for (int k = 0; k < len; ++k) {
      int srcn = csrL[off + k];                 // LDS broadcast to 8 lanes
      unsigned hv = h1h[(size_t)srcn * 8 + q];  // 8 lanes = 32B row
      __half2 p = *reinterpret_cast<const __half2*>(&hv);
      o0 += __low2float(p);
      o1 += __high2float(p);
    }
    float di = dinv[node];
    unsigned sv = h1h[(size_t)node * 8 + q];
    __half2 sh = *reinterpret_cast<const __half2*>(&sv);
    aggS[dl * 16 + 2 * q + 0] = di * (o0 + __low2float(sh));
    aggS[dl * 16 + 2 * q + 1] = di * (o1 + __high2float(sh));
  }
  __syncthreads();

  // ---- phase B: h2 = relu(agg@W2+b2), pool by graph (wave-uniform node) -------
  int c = threadIdx.x & 63;
  int slot = threadIdx.x >> 6;  // 16 waves, one node per wave per iter
  int g0 = batch[b * NPB];      // first graph in bucket (non-decreasing)
  float racc = 0.f;
  int curli = -1;
  for (int nloc = slot; nloc < NPB; nloc += 16) {
    int nd = b * NPB + nloc;
    int li = batch[nd] - g0;    // wave-uniform
    if (li != curli) {
      if (curli >= 0) {
        if (curli < GSPAN) atomicAdd(&gacc[curli * 64 + c], racc);
        else atomicAdd(&gsum[(size_t)(g0 + curli) * 64 + c], racc);
      }
      curli = li;
      racc = 0.f;
    }
    float v = b2s[c];
    const float* ar = &aggS[nloc * 16];
    #pragma unroll
    for (int k = 0; k < 16; ++k) v += ar[k] * w2s[k * 64 + c];  // broadcast reads
    racc += fmaxf(v, 0.f);
  }
  if (curli >= 0) {
    if (curli < GSPAN) atomicAdd(&gacc[curli * 64 + c], racc);
    else atomicAdd(&gsum[(size_t)(g0 + curli) * 64 + c], racc);
  }
  __syncthreads();

  // ---- flush LDS partials to global -------------------------------------------
  int span = batch[b * NPB + NPB - 1] - g0 + 1;
  if (span > GSPAN) span = GSPAN;
  for (int li = threadIdx.x >> 6; li < span; li += 16) {
    float v = gacc[li * 64 + c];
    atomicAdd(&gsum[(size_t)(g0 + li) * 64 + c], v);
  }
}

// ---- final: per-graph mean + FC MLP (64->32->2) --------------------------------
__global__ __launch_bounds__(64) void k_fc(const float* __restrict__ gsum,
                                           const int* __restrict__ batch,
                                           const float* __restrict__ fcw1,
                                           const float* __restrict__ fcb1,
                                           const float* __restrict__ fcw2,
                                           const float* __restrict__ fcb2,
                                           float* __restrict__ out) {
  int g = blockIdx.x;
  int lo = 0, hi = N_NODES;
  while (lo < hi) { int m = (lo + hi) >> 1; if (batch[m] < g) lo = m + 1; else hi = m; }
  int start = lo;
  lo = start; hi = N_NODES;
  while (lo < hi) { int m = (lo + hi) >> 1; if (batch[m] < g + 1) lo = m + 1; else hi = m; }
  float inv = 1.0f / fmaxf((float)(lo - start), 1.0f);

  __shared__ float gmean[64];
  gmean[threadIdx.x] = gsum[(size_t)g * 64 + threadIdx.x] * inv;
  __syncthreads();

  __shared__ float hid[32];
  if (threadIdx.x < 32) {
    float a = fcb1[threadIdx.x];
    #pragma unroll
    for (int k = 0; k < 64; ++k) a += gmean[k] * fcw1[k * 32 + threadIdx.x];
    hid[threadIdx.x] = a;
  }
  __syncthreads();

  if (threadIdx.x < 2) {
    float a = fcb2[threadIdx.x];
    #pragma unroll
    for (int k = 0; k < 32; ++k) a += hid[k] * fcw2[k * 2 + threadIdx.x];
    out[g * 2 + threadIdx.x] = a;
  }
}

extern "C" void kernel_launch(void* const* d_in, const int* in_sizes, int n_in,
                              void* d_out, int out_size, void* d_ws, size_t ws_size,
                              hipStream_t stream) {
  const float* x    = (const float*)d_in[0];
  const int*   ei   = (const int*)d_in[1];
  const int*   batch= (const int*)d_in[2];
  const float* W1   = (const float*)d_in[3];
  const float* b1   = (const float*)d_in[4];
  const float* W2   = (const float*)d_in[5];
  const float* b2   = (const float*)d_in[6];
  const float* fcw1 = (const float*)d_in[7];
  const float* fcb1 = (const float*)d_in[8];
  const float* fcw2 = (const float*)d_in[9];
  const float* fcb2 = (const float*)d_in[10];
  float* out = (float*)d_out;

  char* w = (char*)d_ws;
  size_t off = 0;
  auto alloc = [&](size_t bytes) {
    void* p = w + off;
    off += (bytes + 255) & ~(size_t)255;
    return p;
  };
  int*      bcursor  = (int*)     alloc((size_t)NB * 4);
  unsigned* binned   = (unsigned*)alloc((size_t)NB * BCAP * 4);  // 21 MB
  int*      csrg     = (int*)     alloc((size_t)NB * BCAP * 4);  // 21 MB
  float*    dinv     = (float*)   alloc((size_t)N_NODES * 4);
  float4*   xs4      = (float4*)  alloc((size_t)N_NODES * 16);   // 2 MB
  int*      node_off = (int*)     alloc((size_t)N_NODES * 4);
  int*      cnt      = (int*)     alloc((size_t)N_NODES * 4);
  unsigned* h1h      = (unsigned*)alloc((size_t)N_NODES * 32);   // 4 MB fp16
  float*    gsum     = (float*)   alloc((size_t)NUM_GRAPHS * 64 * 4);

  const int* srcp = ei;
  const int* dstp = ei + N_EDGES;

  hipMemsetAsync(gsum, 0, (size_t)NUM_GRAPHS * 64 * 4, stream);
  k_init<<<1, 512, 0, stream>>>(bcursor);
  k_binfill<<<N_EDGES / 16384, 1024, 0, stream>>>(srcp, dstp, bcursor, binned);
  k_sortB<<<NB, 1024, 0, stream>>>(binned, bcursor, x, dinv, xs4, node_off, cnt, csrg);
  k_agg3h1<<<NB, 1024, 0, stream>>>(csrg, bcursor, node_off, cnt, (const float*)xs4, xs4, dinv, W1, b1, h1h);
  k_agg16pool<<<NB, 1024, 0, stream>>>(csrg, bcursor, node_off, cnt, h1h, dinv, batch, W2, b2, gsum);
  k_fc<<<NUM_GRAPHS, 64, 0, stream>>>(gsum, batch, fcw1, fcb1, fcw2, fcb2, out);
}

// Round 10
// 120.050 us; speedup vs baseline: 1.3459x; 1.0561x over previous
//
#include <hip/hip_runtime.h>
#include <hip/hip_fp16.h>

#define N_NODES 131072
#define N_EDGES 4194304
#define NUM_GRAPHS 128

#define NB 512        // buckets
#define NPB 256       // nodes per bucket (N_NODES / NB)
#define BSHIFT 8      // dst>>8 = bucket, dst&255 = local node
#define BCAP 10240    // slots per bucket (mean 8192, sd ~90 -> +22 sigma)
#define GSPAN 8       // max graphs tracked in LDS per bucket (fallback: global)

typedef int iv4 __attribute__((ext_vector_type(4)));  // NT-loadable int4

// ---------------- init per-bucket cursors -------------------------------------
__global__ __launch_bounds__(512) void k_init(int* __restrict__ bcursor) {
  bcursor[threadIdx.x] = threadIdx.x * BCAP;
}

// ------- bin edges by dst bucket; batch-reserved contiguous runs ---------------
__global__ __launch_bounds__(1024) void k_binfill(const iv4* __restrict__ src4,
                                                  const iv4* __restrict__ dst4,
                                                  int* __restrict__ bcursor,
                                                  unsigned* __restrict__ binned) {
  __shared__ int hist[NB], base_[NB], rank_[NB];
  for (int k = threadIdx.x; k < NB; k += 1024) { hist[k] = 0; rank_[k] = 0; }
  __syncthreads();
  unsigned pk[16];
  int bk[16];
  int q0 = blockIdx.x * 4096 + threadIdx.x;  // int4 index
  #pragma unroll
  for (int i = 0; i < 4; ++i) {
    iv4 sv = __builtin_nontemporal_load(&src4[q0 + i * 1024]);
    iv4 dv = __builtin_nontemporal_load(&dst4[q0 + i * 1024]);
    #pragma unroll
    for (int j = 0; j < 4; ++j) {
      int idx = i * 4 + j;
      int s = sv[j], d = dv[j];
      bk[idx] = d >> BSHIFT;
      pk[idx] = ((unsigned)s << BSHIFT) | (unsigned)(d & (NPB - 1));
      atomicAdd(&hist[bk[idx]], 1);
    }
  }
  __syncthreads();
  for (int k = threadIdx.x; k < NB; k += 1024)
    base_[k] = atomicAdd(&bcursor[k], hist[k]);
  __syncthreads();
  #pragma unroll
  for (int i = 0; i < 16; ++i) {
    int r = atomicAdd(&rank_[bk[i]], 1);
    binned[base_[bk[i]] + r] = pk[i];
  }
}

// ------- per-bucket degree histogram -> dinv, xs = dinv*x (padded float4) ------
__global__ __launch_bounds__(1024) void k_prep(const unsigned* __restrict__ binned,
                                               const int* __restrict__ bcursor,
                                               const float* __restrict__ x,
                                               float* __restrict__ dinv,
                                               float4* __restrict__ xs4) {
  __shared__ int dcount[NPB];
  int tid = threadIdx.x;
  if (tid < NPB) dcount[tid] = 0;
  __syncthreads();
  int b = blockIdx.x;
  int s0 = b * BCAP;
  int n = bcursor[b] - s0;
  for (int e = tid; e < n; e += 1024) {
    unsigned ent = __builtin_nontemporal_load(&binned[s0 + e]);
    atomicAdd(&dcount[ent & (NPB - 1)], 1);
  }
  __syncthreads();
  if (tid < NPB) {
    int node = b * NPB + tid;
    float di = rsqrtf((float)(dcount[tid] + 1));  // +1: self-loop
    dinv[node] = di;
    xs4[node] = make_float4(di * x[node * 3 + 0], di * x[node * 3 + 1],
                            di * x[node * 3 + 2], 0.f);
  }
}

// ---- fused: local counting sort + gather-agg of xs + W1 proj + relu -> fp16 ---
__global__ __launch_bounds__(1024) void k_sagg3h1(const unsigned* __restrict__ binned,
                                                  const int* __restrict__ bcursor,
                                                  const float* __restrict__ xs,
                                                  const float4* __restrict__ xs4,
                                                  const float* __restrict__ dinv,
                                                  const float* __restrict__ W1,
                                                  const float* __restrict__ b1,
                                                  unsigned* __restrict__ h1h) {
  __shared__ int dcount[NPB], cursor[NPB], nbase[NPB];
  __shared__ int wsum[4];
  __shared__ int csrL[BCAP];  // 40 KB, byte offsets (srcn<<4)
  __shared__ float w[48];
  __shared__ float bb[16];
  __shared__ float accS[NPB * 4];
  int tid = threadIdx.x;
  if (tid >= 256 && tid < 304) w[tid - 256] = W1[tid - 256];
  if (tid >= 320 && tid < 336) bb[tid - 320] = b1[tid - 320];
  if (tid < NPB) dcount[tid] = 0;
  __syncthreads();

  int b = blockIdx.x;
  int s0 = b * BCAP;
  int n = bcursor[b] - s0;
  unsigned ent_r[10];
  #pragma unroll
  for (int j = 0; j < 10; ++j) {
    int e = tid + j * 1024;
    if (e < n) {
      unsigned ent = __builtin_nontemporal_load(&binned[s0 + e]);
      ent_r[j] = ent;
      atomicAdd(&dcount[ent & (NPB - 1)], 1);
    }
  }
  __syncthreads();

  int v = 0, incl = 0;
  if (tid < NPB) {
    v = dcount[tid];
    incl = v;
    #pragma unroll
    for (int d = 1; d < 64; d <<= 1) {
      int t = __shfl_up(incl, d);
      if ((tid & 63) >= d) incl += t;
    }
    if ((tid & 63) == 63) wsum[tid >> 6] = incl;
  }
  __syncthreads();
  if (tid < NPB) {
    int base = 0;
    int wv = tid >> 6;
    for (int w2 = 0; w2 < wv; ++w2) base += wsum[w2];
    int pref = base + incl - v;
    cursor[tid] = pref;
    nbase[tid] = pref;
  }
  __syncthreads();

  #pragma unroll
  for (int j = 0; j < 10; ++j) {
    int e = tid + j * 1024;
    if (e < n) {
      unsigned ent = ent_r[j];
      int pos = atomicAdd(&cursor[ent & (NPB - 1)], 1);
      csrL[pos] = (int)(ent >> BSHIFT) << 4;  // byte offset into xs4
    }
  }
  __syncthreads();

  int dl = tid >> 2;
  int q = tid & 3;
  int node = b * NPB + dl;
  int off = nbase[dl];
  int len = dcount[dl];
  const char* xsc = (const char*)xs;
  int qb = q << 2;
  float acc = 0.f;
  #pragma unroll 8
  for (int k = 0; k < len; ++k) {
    int bo = csrL[off + k];                       // LDS broadcast to 4 lanes
    acc += *(const float*)(xsc + bo + qb);        // 4 lanes = 16B row
  }
  accS[tid] = acc;
  __syncthreads();

  float di = dinv[node];
  float4 xself = xs4[node];
  float a0 = di * (accS[dl * 4 + 0] + xself.x);
  float a1 = di * (accS[dl * 4 + 1] + xself.y);
  float a2 = di * (accS[dl * 4 + 2] + xself.z);
  float o[4];
  #pragma unroll
  for (int j = 0; j < 4; ++j) {
    int cc = q * 4 + j;
    float vv = a0 * w[cc] + a1 * w[16 + cc] + a2 * w[32 + cc] + bb[cc];
    o[j] = di * fmaxf(vv, 0.f);
  }
  __half2 p0 = __floats2half2_rn(o[0], o[1]);
  __half2 p1 = __floats2half2_rn(o[2], o[3]);
  uint2 st;
  st.x = *reinterpret_cast<unsigned*>(&p0);
  st.y = *reinterpret_cast<unsigned*>(&p1);
  *(uint2*)(h1h + (size_t)node * 8 + q * 2) = st;
}

// ---- fused: local sort + gather-agg h1 + h2=relu(agg@W2+b2) + graph pool ------
__global__ __launch_bounds__(1024) void k_sagg16pool(const unsigned* __restrict__ binned,
                                                     const int* __restrict__ bcursor,
                                                     const unsigned* __restrict__ h1h,
                                                     const float* __restrict__ dinv,
                                                     const int* __restrict__ batch,
                                                     const float* __restrict__ W2,
                                                     const float* __restrict__ b2,
                                                     float* __restrict__ gsum) {
  __shared__ int dcount[NPB], cursor[NPB], nbase[NPB];
  __shared__ int wsum[4];
  __shared__ int csrL[BCAP];         // 40 KB, byte offsets (srcn<<5)
  __shared__ float aggS[NPB * 16];   // 16 KB
  __shared__ float w2s[1024];        // 4 KB
  __shared__ float b2s[64];
  __shared__ float gacc[GSPAN * 64]; // 2 KB
  int tid = threadIdx.x;
  w2s[tid] = W2[tid];
  if (tid < 64) b2s[tid] = b2[tid];
  if (tid < GSPAN * 64) gacc[tid] = 0.f;
  if (tid < NPB) dcount[tid] = 0;
  __syncthreads();

  int b = blockIdx.x;
  int s0 = b * BCAP;
  int n = bcursor[b] - s0;
  unsigned ent_r[10];
  #pragma unroll
  for (int j = 0; j < 10; ++j) {
    int e = tid + j * 1024;
    if (e < n) {
      unsigned ent = __builtin_nontemporal_load(&binned[s0 + e]);
      ent_r[j] = ent;
      atomicAdd(&dcount[ent & (NPB - 1)], 1);
    }
  }
  __syncthreads();

  int v = 0, incl = 0;
  if (tid < NPB) {
    v = dcount[tid];
    incl = v;
    #pragma unroll
    for (int d = 1; d < 64; d <<= 1) {
      int t = __shfl_up(incl, d);
      if ((tid & 63) >= d) incl += t;
    }
    if ((tid & 63) == 63) wsum[tid >> 6] = incl;
  }
  __syncthreads();
  if (tid < NPB) {
    int base = 0;
    int wv = tid >> 6;
    for (int w2 = 0; w2 < wv; ++w2) base += wsum[w2];
    int pref = base + incl - v;
    cursor[tid] = pref;
    nbase[tid] = pref;
  }
  __syncthreads();

  #pragma unroll
  for (int j = 0; j < 10; ++j) {
    int e = tid + j * 1024;
    if (e < n) {
      unsigned ent = ent_r[j];
      int pos = atomicAdd(&cursor[ent & (NPB - 1)], 1);
      csrL[pos] = (int)(ent >> BSHIFT) << 5;  // byte offset into h1h rows
    }
  }
  __syncthreads();

  // ---- phase A: per-node aggregation into LDS (8 lanes/node, 2 halves) --------
  const char* h1c = (const char*)h1h;
  int q = tid & 7;
  int qb = q << 2;
  int nl0 = tid >> 3;
  #pragma unroll
  for (int half = 0; half < 2; ++half) {
    int dl = nl0 + half * 128;
    int node = b * NPB + dl;
    int off = nbase[dl];
    int len = dcount[dl];
    float o0 = 0.f, o1 = 0.f;
    #pragma unroll 8
    for (int k = 0; k < len; ++k) {
      int bo = csrL[off + k];                             // LDS broadcast
      unsigned hv = *(const unsigned*)(h1c + bo + qb);    // 8 lanes = 32B row
      __half2 p = *reinterpret_cast<const __half2*>(&hv);
      o0 += __low2float(p);
      o1 += __high2float(p);
    }
    float di = dinv[node];
    unsigned sv = h1h[(size_t)node * 8 + q];
    __half2 sh = *reinterpret_cast<const __half2*>(&sv);
    aggS[dl * 16 + 2 * q + 0] = di * (o0 + __low2float(sh));
    aggS[dl * 16 + 2 * q + 1] = di * (o1 + __high2float(sh));
  }
  __syncthreads();

  // ---- phase B: h2 = relu(agg@W2+b2), pool by graph (wave-uniform node) -------
  int c = tid & 63;
  int slot = tid >> 6;  // 16 waves
  int g0 = batch[b * NPB];
  float racc = 0.f;
  int curli = -1;
  for (int nloc = slot; nloc < NPB; nloc += 16) {
    int nd = b * NPB + nloc;
    int li = batch[nd] - g0;
    if (li != curli) {
      if (curli >= 0) {
        if (curli < GSPAN) atomicAdd(&gacc[curli * 64 + c], racc);
        else atomicAdd(&gsum[(size_t)(g0 + curli) * 64 + c], racc);
      }
      curli = li;
      racc = 0.f;
    }
    float vv = b2s[c];
    const float* ar = &aggS[nloc * 16];
    #pragma unroll
    for (int k = 0; k < 16; ++k) vv += ar[k] * w2s[k * 64 + c];
    racc += fmaxf(vv, 0.f);
  }
  if (curli >= 0) {
    if (curli < GSPAN) atomicAdd(&gacc[curli * 64 + c], racc);
    else atomicAdd(&gsum[(size_t)(g0 + curli) * 64 + c], racc);
  }
  __syncthreads();

  int span = batch[b * NPB + NPB - 1] - g0 + 1;
  if (span > GSPAN) span = GSPAN;
  for (int li = tid >> 6; li < span; li += 16) {
    atomicAdd(&gsum[(size_t)(g0 + li) * 64 + c], gacc[li * 64 + c]);
  }
}

// ---- final: per-graph mean + FC MLP (64->32->2) --------------------------------
__global__ __launch_bounds__(64) void k_fc(const float* __restrict__ gsum,
                                           const int* __restrict__ batch,
                                           const float* __restrict__ fcw1,
                                           const float* __restrict__ fcb1,
                                           const float* __restrict__ fcw2,
                                           const float* __restrict__ fcb2,
                                           float* __restrict__ out) {
  int g = blockIdx.x;
  int lo = 0, hi = N_NODES;
  while (lo < hi) { int m = (lo + hi) >> 1; if (batch[m] < g) lo = m + 1; else hi = m; }
  int start = lo;
  lo = start; hi = N_NODES;
  while (lo < hi) { int m = (lo + hi) >> 1; if (batch[m] < g + 1) lo = m + 1; else hi = m; }
  float inv = 1.0f / fmaxf((float)(lo - start), 1.0f);

  __shared__ float gmean[64];
  gmean[threadIdx.x] = gsum[(size_t)g * 64 + threadIdx.x] * inv;
  __syncthreads();

  __shared__ float hid[32];
  if (threadIdx.x < 32) {
    float a = fcb1[threadIdx.x];
    #pragma unroll
    for (int k = 0; k < 64; ++k) a += gmean[k] * fcw1[k * 32 + threadIdx.x];
    hid[threadIdx.x] = a;
  }
  __syncthreads();

  if (threadIdx.x < 2) {
    float a = fcb2[threadIdx.x];
    #pragma unroll
    for (int k = 0; k < 32; ++k) a += hid[k] * fcw2[k * 2 + threadIdx.x];
    out[g * 2 + threadIdx.x] = a;
  }
}

extern "C" void kernel_launch(void* const* d_in, const int* in_sizes, int n_in,
                              void* d_out, int out_size, void* d_ws, size_t ws_size,
                              hipStream_t stream) {
  const float* x    = (const float*)d_in[0];
  const int*   ei   = (const int*)d_in[1];
  const int*   batch= (const int*)d_in[2];
  const float* W1   = (const float*)d_in[3];
  const float* b1   = (const float*)d_in[4];
  const float* W2   = (const float*)d_in[5];
  const float* b2   = (const float*)d_in[6];
  const float* fcw1 = (const float*)d_in[7];
  const float* fcb1 = (const float*)d_in[8];
  const float* fcw2 = (const float*)d_in[9];
  const float* fcb2 = (const float*)d_in[10];
  float* out = (float*)d_out;

  char* w = (char*)d_ws;
  size_t off = 0;
  auto alloc = [&](size_t bytes) {
    void* p = w + off;
    off += (bytes + 255) & ~(size_t)255;
    return p;
  };
  int*      bcursor = (int*)     alloc((size_t)NB * 4);
  unsigned* binned  = (unsigned*)alloc((size_t)NB * BCAP * 4);  // 21 MB
  float*    dinv    = (float*)   alloc((size_t)N_NODES * 4);
  float4*   xs4     = (float4*)  alloc((size_t)N_NODES * 16);   // 2 MB
  unsigned* h1h     = (unsigned*)alloc((size_t)N_NODES * 32);   // 4 MB fp16
  float*    gsum    = (float*)   alloc((size_t)NUM_GRAPHS * 64 * 4);

  const iv4* src4 = (const iv4*)ei;
  const iv4* dst4 = (const iv4*)(ei + N_EDGES);

  hipMemsetAsync(gsum, 0, (size_t)NUM_GRAPHS * 64 * 4, stream);
  k_init<<<1, 512, 0, stream>>>(bcursor);
  k_binfill<<<N_EDGES / 16384, 1024, 0, stream>>>(src4, dst4, bcursor, binned);
  k_prep<<<NB, 1024, 0, stream>>>(binned, bcursor, x, dinv, xs4);
  k_sagg3h1<<<NB, 1024, 0, stream>>>(binned, bcursor, (const float*)xs4, xs4, dinv, W1, b1, h1h);
  k_sagg16pool<<<NB, 1024, 0, stream>>>(binned, bcursor, h1h, dinv, batch, W2, b2, gsum);
  k_fc<<<NUM_GRAPHS, 64, 0, stream>>>(gsum, batch, fcw1, fcb1, fcw2, fcb2, out);
}